// Round 9
// baseline (1988.092 us; speedup 1.0000x reference)
//
#include <hip/hip_runtime.h>

typedef unsigned short u16;
typedef unsigned int u32;
typedef _Float16 f16;
typedef _Float16 half8 __attribute__((ext_vector_type(8)));
typedef _Float16 half4 __attribute__((ext_vector_type(4)));
typedef float f32x4 __attribute__((ext_vector_type(4)));

#define SPLIT_SC 2048.0f
#define SPLIT_INV (1.0f / 2048.0f)

__device__ __forceinline__ float sigf(float x) { return 1.0f / (1.0f + expf(-x)); }

// Fragment-layout address for value (row=b/k-dim unit): plane-split pairs at
// ((kc*64 + rt)*2 + plane)*512 + lane_dst*8 + j,  kc=k>>5, rt=row>>4,
// lane_dst=((k&31)>>3)*16 + (row&15), j=k&7.
__device__ __forceinline__ size_t frag_addr(int row, int k) {
    return ((size_t)((k >> 5) * 64 + (row >> 4)) * 2) * 512
         + (size_t)((((k & 31) >> 3) << 4) + (row & 15)) * 8 + (k & 7);
}

// ---------------------------------------------------------------------------
// Fused attention-params + filterbank + glimpse, v3.
// One block per (batch, channel): grid (1024, 3).
// h read from fragment layout; r written in fragment layout (for gates GEMM).
// ---------------------------------------------------------------------------
__global__ __launch_bounds__(256) void att_glimpse(
    const f16* __restrict__ hs,                 // h fragment-layout (K=1024)
    const float* __restrict__ Watt, const float* __restrict__ batt,
    const float* __restrict__ x,
    f16* __restrict__ r_swz)                    // r fragment-layout (K=768)
{
    __shared__ float simg[64 * 64];      // 16 KB, this channel, [y][a]
    __shared__ float sFx[16 * 68];       // [xo][a], stride 68
    __shared__ float sFyT[64 * 20];      // [y][n],  stride 20
    __shared__ float stmp[16 * 68];      // [n][a],  stride 68
    __shared__ float sred[4 * 5];
    __shared__ float spar[8];

    const int b = blockIdx.x, c = blockIdx.y, tid = threadIdx.x;
    const int lane = tid & 63, wave = tid >> 6;

    // stage img channel slice into LDS fp32 (1024 float4)
    {
        const float4* src = (const float4*)(x + (size_t)b * 12288 + c * 4096);
        float4* dst = (float4*)simg;
        for (int i = tid; i < 1024; i += 256) dst[i] = src[i];
    }

    // phase A: p = h[b] @ Watt^T + batt (5 dots of length 1024), fp32
    float p[5] = {0.f, 0.f, 0.f, 0.f, 0.f};
    {
        for (int k = tid; k < 1024; k += 256) {
            size_t ba = frag_addr(b, k);
            float hv = (float)hs[ba] + (float)hs[ba + 512] * SPLIT_INV;
#pragma unroll
            for (int j = 0; j < 5; j++) p[j] += hv * Watt[j * 1024 + k];
        }
#pragma unroll
        for (int j = 0; j < 5; j++) {
#pragma unroll
            for (int o = 32; o > 0; o >>= 1) p[j] += __shfl_xor(p[j], o);
        }
        if (lane == 0) {
#pragma unroll
            for (int j = 0; j < 5; j++) sred[wave * 5 + j] = p[j];
        }
    }
    __syncthreads();
    if (tid == 0) {
        float q[5];
#pragma unroll
        for (int j = 0; j < 5; j++)
            q[j] = sred[j] + sred[5 + j] + sred[10 + j] + sred[15 + j] + batt[j];
        float q2 = fminf(fmaxf(q[2], -60.f), 60.f);
        float q3 = fminf(fmaxf(q[3], -60.f), 60.f);
        float q4 = fminf(fmaxf(q[4], -60.f), 60.f);
        spar[0] = 32.5f * (q[0] + 1.0f);          // gx
        spar[1] = 32.5f * (q[1] + 1.0f);          // gy
        spar[2] = 0.5f * expf(-q2);               // 1/(2*sigma2)
        spar[3] = 4.2f * expf(q3);                // delta
        spar[4] = expf(q4);                       // gamma
    }
    __syncthreads();
    const float gx = spar[0], gy = spar[1], inv2s2 = spar[2], dl = spar[3],
                gamma = spar[4];

    // phase B: filterbank.  wave w handles n = w, w+4, w+8, w+12; lane = pixel
    {
        const float af = (float)lane;
#pragma unroll
        for (int i = 0; i < 4; i++) {
            int n = wave + i * 4;
            float nn = (float)n - 8.5f;
            float mux = gx + nn * dl;
            float ex = af - mux;
            float vx = expf(-ex * ex * inv2s2);
            float sx = vx;
#pragma unroll
            for (int o = 32; o > 0; o >>= 1) sx += __shfl_xor(sx, o);
            sFx[n * 68 + lane] = vx / (sx + 1e-8f);

            float muy = gy + nn * dl;
            float ey = af - muy;
            float vy = expf(-ey * ey * inv2s2);
            float sy = vy;
#pragma unroll
            for (int o = 32; o > 0; o >>= 1) sy += __shfl_xor(sy, o);
            sFyT[lane * 20 + n] = vy / (sy + 1e-8f);   // transposed [y][n]
        }
    }
    __syncthreads();

    // stage 1 (wave 0 only): tmp[n][a] = sum_y Fy[n][y] * img[y][a]
    if (wave == 0) {
        const int n4 = lane >> 4, a4 = lane & 15;
        f32x4 acc[4];
#pragma unroll
        for (int j = 0; j < 4; j++) acc[j] = (f32x4)(0.f);
        for (int y = 0; y < 64; y++) {
            float4 im = *(const float4*)(simg + y * 64 + a4 * 4);
            float4 fy = *(const float4*)(sFyT + y * 20 + n4 * 4);
            f32x4 iv = {im.x, im.y, im.z, im.w};
            acc[0] += fy.x * iv;
            acc[1] += fy.y * iv;
            acc[2] += fy.z * iv;
            acc[3] += fy.w * iv;
        }
#pragma unroll
        for (int j = 0; j < 4; j++)
            *(f32x4*)(stmp + (n4 * 4 + j) * 68 + a4 * 4) = acc[j];
    }
    __syncthreads();

    // stage 2: r[n][xo] = gamma * sum_a tmp[n][a] * Fx[xo][a] -> fragment store
    {
        const int n = tid >> 4, xo = tid & 15;
        const float* tp = stmp + n * 68;
        const float* fx = sFx + xo * 68;
        float s = 0.f;
        for (int a = 0; a < 64; a += 4) {
            float4 t4 = *(const float4*)(tp + a);
            float4 x4 = *(const float4*)(fx + a);
            s += t4.x * x4.x + t4.y * x4.y + t4.z * x4.z + t4.w * x4.w;
        }
        float v = s * gamma;
        f16 hi = (f16)v;
        int k = c * 256 + tid;               // K-dim index, 0..767
        size_t ba = frag_addr(b, k);
        r_swz[ba] = hi;
        r_swz[ba + 512] = (f16)((v - (float)hi) * SPLIT_SC);
    }
}

// ---------------------------------------------------------------------------
// W pre-swizzle: W_ih||W_hh fp32 -> split-f16 pair in MFMA B-fragment order.
// (unchanged from round 7 — verified)
// ---------------------------------------------------------------------------
__global__ __launch_bounds__(256) void swz_w(
    const float* __restrict__ W1, const float* __restrict__ W2,
    f16* __restrict__ out)
{
    const int kc = blockIdx.x >> 5, bn = blockIdx.x & 31;
    for (int t = threadIdx.x; t < 512; t += 256) {
        int c = t >> 6, lane = t & 63, l15 = lane & 15, lq = lane >> 4;
        int wrow = (c & 3) * 1024 + bn * 32 + l15 + ((c >> 2) << 4);
        const float* src;
        if (kc < 24) src = W1 + (size_t)wrow * 768 + kc * 32 + lq * 8;
        else         src = W2 + (size_t)wrow * 1024 + (kc - 24) * 32 + lq * 8;
        float4 g0 = *(const float4*)src;
        float4 g1 = *(const float4*)(src + 4);
        float gv[8] = {g0.x, g0.y, g0.z, g0.w, g1.x, g1.y, g1.z, g1.w};
        half8 hv, lv;
#pragma unroll
        for (int j = 0; j < 8; j++) {
            f16 h = (f16)gv[j];
            hv[j] = h;
            lv[j] = (f16)((gv[j] - (float)h) * SPLIT_SC);
        }
        size_t base = ((size_t)(kc * 32 + bn) * 16 + c * 2) * 512 + (size_t)lane * 8;
        *(half8*)(out + base) = hv;
        *(half8*)(out + base + 512) = lv;
    }
}

// ---------------------------------------------------------------------------
// W_fc0 pre-swizzle: [kc 0..31][cn 0..15][ct 0..3][plane][lane][8]
// ---------------------------------------------------------------------------
__global__ __launch_bounds__(256) void swz_wfc(
    const float* __restrict__ W, f16* __restrict__ out)
{
    const int kc = blockIdx.x >> 4, cn = blockIdx.x & 15;
    const int ct = threadIdx.x >> 6, lane = threadIdx.x & 63;
    const int l15 = lane & 15, lq = lane >> 4;
    int wrow = cn * 64 + ct * 16 + l15;
    const float* src = W + (size_t)wrow * 1024 + kc * 32 + lq * 8;
    float4 g0 = *(const float4*)src;
    float4 g1 = *(const float4*)(src + 4);
    float gv[8] = {g0.x, g0.y, g0.z, g0.w, g1.x, g1.y, g1.z, g1.w};
    half8 hv, lv;
#pragma unroll
    for (int j = 0; j < 8; j++) {
        f16 h = (f16)gv[j];
        hv[j] = h;
        lv[j] = (f16)((gv[j] - (float)h) * SPLIT_SC);
    }
    size_t base = ((size_t)(kc * 16 + cn) * 8 + ct * 2) * 512 + (size_t)lane * 8;
    *(half8*)(out + base) = hv;
    *(half8*)(out + base + 512) = lv;
}

// ---------------------------------------------------------------------------
// Fused gates GEMM + LSTM pointwise, v5: barrier-free, LDS-free.
// Block = 128 rows x 128 crows; grid 256 = 1 block/CU; wave = 64x64.
// A (r,h) and B (W) all loaded as pre-swizzled MFMA fragments (coalesced
// 1 KB wave-loads), 48 MFMA per wave-iter, no __syncthreads in the K loop.
// ---------------------------------------------------------------------------
__global__ __launch_bounds__(256, 1) void gates_lstm(
    const f16* __restrict__ r_swz,   // A frags, kc 0..23
    const f16* __restrict__ h_swz,   // A frags, kc 24..55
    const f16* __restrict__ Wswz,
    const float* __restrict__ b1, const float* __restrict__ b2,
    float* __restrict__ cst,
    f16* __restrict__ Hout)          // h write, fragment layout
{
    const int tid = threadIdx.x;
    const int kb = blockIdx.x;            // 0..255
    const int xcd = kb & 7, jb = kb >> 3; // XCD swizzle: bn group per XCD
    const int bn = xcd * 4 + (jb & 3);    // 0..31
    const int bm = jb >> 2;               // 0..7  (128-row tiles)
    const int wave = tid >> 6, lane = tid & 63;
    const int wrow = wave >> 1;           // 64-row half
    const int wcol = wave & 1;            // c-tile half (4 c-tiles each)
    const int l15 = lane & 15, lq = lane >> 4;
    const int rtb = bm * 8 + wrow * 4;    // A row-tile base

    f32x4 ah[4][4], al[4][4];
#pragma unroll
    for (int i = 0; i < 4; i++)
#pragma unroll
        for (int j = 0; j < 4; j++) { ah[i][j] = (f32x4)(0.f); al[i][j] = (f32x4)(0.f); }

#pragma unroll 2
    for (int kc = 0; kc < 56; ++kc) {
        const f16* Ab; size_t ak;
        if (kc < 24) { Ab = r_swz; ak = (size_t)kc * 64; }
        else         { Ab = h_swz; ak = (size_t)(kc - 24) * 64; }
        half8 afh[4], afl[4], bfh[4], bfl[4];
#pragma unroll
        for (int mt = 0; mt < 4; mt++) {
            const f16* p = Ab + ((ak + rtb + mt) * 2) * 512 + lane * 8;
            afh[mt] = *(const half8*)p;
            afl[mt] = *(const half8*)(p + 512);
        }
        const f16* wb = Wswz + ((size_t)(kc * 32 + bn) * 16 + wcol * 8) * 512
                      + (size_t)lane * 8;
#pragma unroll
        for (int nt = 0; nt < 4; nt++) {
            bfh[nt] = *(const half8*)(wb + nt * 1024);
            bfl[nt] = *(const half8*)(wb + nt * 1024 + 512);
        }
#pragma unroll
        for (int mt = 0; mt < 4; mt++)
#pragma unroll
            for (int nt = 0; nt < 4; nt++) {
                ah[mt][nt] = __builtin_amdgcn_mfma_f32_16x16x32_f16(
                    afh[mt], bfh[nt], ah[mt][nt], 0, 0, 0);
                al[mt][nt] = __builtin_amdgcn_mfma_f32_16x16x32_f16(
                    afh[mt], bfl[nt], al[mt][nt], 0, 0, 0);
                al[mt][nt] = __builtin_amdgcn_mfma_f32_16x16x32_f16(
                    afl[mt], bfh[nt], al[mt][nt], 0, 0, 0);
            }
    }

    // epilogue: gate = nt; u = bn*32 + l15 + wcol*16; rows over (mt, rg)
    const int u = bn * 32 + l15 + (wcol << 4);
    float bvs[4];
#pragma unroll
    for (int g = 0; g < 4; g++) bvs[g] = b1[g * 1024 + u] + b2[g * 1024 + u];
#pragma unroll
    for (int mt = 0; mt < 4; mt++) {
#pragma unroll
        for (int rg = 0; rg < 4; rg++) {
            int row = bm * 128 + wrow * 64 + mt * 16 + lq * 4 + rg;
            size_t idx = (size_t)row * 1024 + u;
            float gi = ah[mt][0][rg] + al[mt][0][rg] * SPLIT_INV + bvs[0];
            float gf = ah[mt][1][rg] + al[mt][1][rg] * SPLIT_INV + bvs[1];
            float gg = ah[mt][2][rg] + al[mt][2][rg] * SPLIT_INV + bvs[2];
            float go = ah[mt][3][rg] + al[mt][3][rg] * SPLIT_INV + bvs[3];
            float cn = sigf(gf) * cst[idx] + sigf(gi) * tanhf(gg);
            float hn = sigf(go) * tanhf(cn);
            cst[idx] = cn;
            f16 hh = (f16)hn;
            size_t ba = frag_addr(row, u);
            Hout[ba] = hh;
            Hout[ba + 512] = (f16)((hn - (float)hh) * SPLIT_SC);
        }
    }
}

// ---------------------------------------------------------------------------
// fc0 v2: t = relu(h @ W_fc0^T + b), barrier-free fragment GEMM.
// Grid 256 blocks (bm 0..15 x cn 0..15); 4 waves, wave = 64 rows x 16 cols.
// ---------------------------------------------------------------------------
__global__ __launch_bounds__(256, 1) void fc0_gemm(
    const f16* __restrict__ h_swz, const f16* __restrict__ Wf,
    const float* __restrict__ bias, float* __restrict__ out)
{
    const int tid = threadIdx.x;
    const int bm = blockIdx.x >> 4, cn = blockIdx.x & 15;
    const int wave = tid >> 6, lane = tid & 63;
    const int l15 = lane & 15, lq = lane >> 4;

    f32x4 ah[4], al[4];
#pragma unroll
    for (int i = 0; i < 4; i++) { ah[i] = (f32x4)(0.f); al[i] = (f32x4)(0.f); }

#pragma unroll 2
    for (int kc = 0; kc < 32; ++kc) {
        half8 afh[4], afl[4];
#pragma unroll
        for (int mt = 0; mt < 4; mt++) {
            const f16* p = h_swz + ((size_t)(kc * 64 + bm * 4 + mt) * 2) * 512
                         + (size_t)lane * 8;
            afh[mt] = *(const half8*)p;
            afl[mt] = *(const half8*)(p + 512);
        }
        const f16* wb = Wf + ((size_t)(kc * 16 + cn) * 8 + wave * 2) * 512
                      + (size_t)lane * 8;
        half8 bfh = *(const half8*)wb;
        half8 bfl = *(const half8*)(wb + 512);
#pragma unroll
        for (int mt = 0; mt < 4; mt++) {
            ah[mt] = __builtin_amdgcn_mfma_f32_16x16x32_f16(afh[mt], bfh, ah[mt], 0, 0, 0);
            al[mt] = __builtin_amdgcn_mfma_f32_16x16x32_f16(afh[mt], bfl, al[mt], 0, 0, 0);
            al[mt] = __builtin_amdgcn_mfma_f32_16x16x32_f16(afl[mt], bfh, al[mt], 0, 0, 0);
        }
    }

    const int col = cn * 64 + wave * 16 + l15;
    const float bv = bias[col];
#pragma unroll
    for (int mt = 0; mt < 4; mt++) {
#pragma unroll
        for (int rg = 0; rg < 4; rg++) {
            int row = bm * 64 + mt * 16 + lq * 4 + rg;
            float v = ah[mt][rg] + al[mt][rg] * SPLIT_INV + bv;
            out[(size_t)row * 1024 + col] = fmaxf(v, 0.f);
        }
    }
}

// ---------------------------------------------------------------------------
// final tiny fc: out[b][j] = t[b] . W_fc[j] + b_fc[j], j < 10, fp32 out
// ---------------------------------------------------------------------------
__global__ __launch_bounds__(64) void fc_out(
    const float* __restrict__ tb, const float* __restrict__ Wfc,
    const float* __restrict__ bfc, float* __restrict__ out)
{
    int b = blockIdx.x, lane = threadIdx.x;
    const float* tv = tb + (size_t)b * 1024;
    float p[10];
#pragma unroll
    for (int j = 0; j < 10; j++) p[j] = 0.f;
    for (int k = lane; k < 1024; k += 64) {
        float t = tv[k];
#pragma unroll
        for (int j = 0; j < 10; j++) p[j] += t * Wfc[j * 1024 + k];
    }
#pragma unroll
    for (int j = 0; j < 10; j++) {
#pragma unroll
        for (int o = 32; o > 0; o >>= 1) p[j] += __shfl_xor(p[j], o);
    }
    if (lane == 0) {
#pragma unroll
        for (int j = 0; j < 10; j++) out[b * 10 + j] = p[j] + bfc[j];
    }
}

extern "C" void kernel_launch(void* const* d_in, const int* in_sizes, int n_in,
                              void* d_out, int out_size, void* d_ws, size_t ws_size,
                              hipStream_t stream)
{
    const float* x     = (const float*)d_in[0];
    const float* W_att = (const float*)d_in[1];
    const float* b_att = (const float*)d_in[2];
    const float* W_ih  = (const float*)d_in[3];
    const float* W_hh  = (const float*)d_in[4];
    const float* b_ih  = (const float*)d_in[5];
    const float* b_hh  = (const float*)d_in[6];
    const float* W_fc0 = (const float*)d_in[7];
    const float* b_fc0 = (const float*)d_in[8];
    const float* W_fc  = (const float*)d_in[9];
    const float* b_fc  = (const float*)d_in[10];
    float* out = (float*)d_out;

    // Workspace (~48.4 MB): Wswz | Wfcswz | c | h_swz x2 | r_swz; t overlays c
    char* ws = (char*)d_ws;
    f16*   Wswz   = (f16*)ws;    ws += (size_t)56 * 32 * 16 * 512 * 2;  // 29.36 MB
    f16*   Wfcswz = (f16*)ws;    ws += (size_t)32 * 16 * 8 * 512 * 2;   // 4 MB
    float* c_f32  = (float*)ws;  ws += (size_t)1024 * 1024 * 4;         // 4 MB
    f16*   h_swz0 = (f16*)ws;    ws += (size_t)32 * 64 * 2 * 512 * 2;   // 4 MB
    f16*   h_swz1 = (f16*)ws;    ws += (size_t)32 * 64 * 2 * 512 * 2;   // 4 MB
    f16*   r_swz  = (f16*)ws;    ws += (size_t)24 * 64 * 2 * 512 * 2;   // 3 MB
    float* t_f32  = c_f32;  // overlay: c dead after last gates_lstm
    f16* h_swz[2] = {h_swz0, h_swz1};

    hipMemsetAsync(c_f32, 0, (size_t)1024 * 1024 * 4, stream);
    hipMemsetAsync(h_swz0, 0, (size_t)32 * 64 * 2 * 512 * 2, stream);

    swz_w<<<56 * 32, 256, 0, stream>>>(W_ih, W_hh, Wswz);
    swz_wfc<<<32 * 16, 256, 0, stream>>>(W_fc0, Wfcswz);

    for (int t = 0; t < 16; t++) {
        int rb = t & 1, wb = 1 - rb;
        att_glimpse<<<dim3(1024, 3), 256, 0, stream>>>(
            h_swz[rb], W_att, b_att, x, r_swz);
        gates_lstm<<<256, 256, 0, stream>>>(
            r_swz, h_swz[rb], Wswz, b_ih, b_hh, c_f32, h_swz[wb]);
    }
    fc0_gemm<<<256, 256, 0, stream>>>(h_swz[0], Wfcswz, b_fc0, t_f32);
    fc_out<<<1024, 64, 0, stream>>>(t_f32, W_fc, b_fc, out);
}

// Round 10
// 1461.533 us; speedup vs baseline: 1.3603x; 1.3603x over previous
//
#include <hip/hip_runtime.h>

typedef unsigned short u16;
typedef unsigned int u32;
typedef _Float16 f16;
typedef _Float16 half8 __attribute__((ext_vector_type(8)));
typedef _Float16 half4 __attribute__((ext_vector_type(4)));
typedef float f32x4 __attribute__((ext_vector_type(4)));

#define SPLIT_SC 2048.0f
#define SPLIT_INV (1.0f / 2048.0f)

__device__ __forceinline__ float sigf(float x) { return 1.0f / (1.0f + expf(-x)); }

// ---------------------------------------------------------------------------
// Fused attention-params + filterbank + glimpse, v4.
// One block per (batch, channel): grid (1024, 3).  LDS ~30 KB -> 5 blk/CU.
// Stage 1 now uses ALL 4 waves: wave w owns n-quad w; lanes split y in 4
// chunks (ysub = lane>>4), partials combined via shfl_xor(16/32).
// ---------------------------------------------------------------------------
__global__ __launch_bounds__(256) void att_glimpse(
    const f16* __restrict__ h_hi, const f16* __restrict__ h_lo,
    const float* __restrict__ Watt, const float* __restrict__ batt,
    const float* __restrict__ x,
    f16* __restrict__ r_hi, f16* __restrict__ r_lo)
{
    __shared__ float simg[64 * 64];      // 16 KB, this channel, [y][a]
    __shared__ float sFx[16 * 68];       // [xo][a], stride 68
    __shared__ float sFyT[64 * 20];      // [y][n],  stride 20
    __shared__ float stmp[16 * 68];      // [n][a],  stride 68
    __shared__ float sred[4 * 5];
    __shared__ float spar[8];

    const int b = blockIdx.x, c = blockIdx.y, tid = threadIdx.x;
    const int lane = tid & 63, wave = tid >> 6;

    // stage img channel slice into LDS fp32 (1024 float4)
    {
        const float4* src = (const float4*)(x + (size_t)b * 12288 + c * 4096);
        float4* dst = (float4*)simg;
        for (int i = tid; i < 1024; i += 256) dst[i] = src[i];
    }

    // phase A: p = h[b] @ Watt^T + batt (5 dots of length 1024), fp32
    float p[5] = {0.f, 0.f, 0.f, 0.f, 0.f};
    {
        const f16* hh = h_hi + (size_t)b * 1024;
        const f16* hl = h_lo + (size_t)b * 1024;
        for (int k = tid; k < 1024; k += 256) {
            float hv = (float)hh[k] + (float)hl[k] * SPLIT_INV;
#pragma unroll
            for (int j = 0; j < 5; j++) p[j] += hv * Watt[j * 1024 + k];
        }
#pragma unroll
        for (int j = 0; j < 5; j++) {
#pragma unroll
            for (int o = 32; o > 0; o >>= 1) p[j] += __shfl_xor(p[j], o);
        }
        if (lane == 0) {
#pragma unroll
            for (int j = 0; j < 5; j++) sred[wave * 5 + j] = p[j];
        }
    }
    __syncthreads();
    if (tid == 0) {
        float q[5];
#pragma unroll
        for (int j = 0; j < 5; j++)
            q[j] = sred[j] + sred[5 + j] + sred[10 + j] + sred[15 + j] + batt[j];
        float q2 = fminf(fmaxf(q[2], -60.f), 60.f);
        float q3 = fminf(fmaxf(q[3], -60.f), 60.f);
        float q4 = fminf(fmaxf(q[4], -60.f), 60.f);
        spar[0] = 32.5f * (q[0] + 1.0f);          // gx
        spar[1] = 32.5f * (q[1] + 1.0f);          // gy
        spar[2] = 0.5f * expf(-q2);               // 1/(2*sigma2)
        spar[3] = 4.2f * expf(q3);                // delta
        spar[4] = expf(q4);                       // gamma
    }
    __syncthreads();
    const float gx = spar[0], gy = spar[1], inv2s2 = spar[2], dl = spar[3],
                gamma = spar[4];

    // phase B: filterbank.  wave w handles n = w, w+4, w+8, w+12; lane = pixel
    {
        const float af = (float)lane;
#pragma unroll
        for (int i = 0; i < 4; i++) {
            int n = wave + i * 4;
            float nn = (float)n - 8.5f;
            float mux = gx + nn * dl;
            float ex = af - mux;
            float vx = expf(-ex * ex * inv2s2);
            float sx = vx;
#pragma unroll
            for (int o = 32; o > 0; o >>= 1) sx += __shfl_xor(sx, o);
            sFx[n * 68 + lane] = vx / (sx + 1e-8f);

            float muy = gy + nn * dl;
            float ey = af - muy;
            float vy = expf(-ey * ey * inv2s2);
            float sy = vy;
#pragma unroll
            for (int o = 32; o > 0; o >>= 1) sy += __shfl_xor(sy, o);
            sFyT[lane * 20 + n] = vy / (sy + 1e-8f);   // transposed [y][n]
        }
    }
    __syncthreads();

    // stage 1 (all 4 waves): tmp[n][a] = sum_y Fy[n][y] * img[y][a]
    // wave owns n-quad = wave; lane: ysub = lane>>4 (y chunk), a4 = lane&15
    {
        const int n4 = wave, ysub = lane >> 4, a4 = lane & 15;
        f32x4 acc[4];
#pragma unroll
        for (int j = 0; j < 4; j++) acc[j] = (f32x4)(0.f);
        for (int yy = 0; yy < 16; yy++) {
            int y = ysub * 16 + yy;
            float4 im = *(const float4*)(simg + y * 64 + a4 * 4);
            float4 fy = *(const float4*)(sFyT + y * 20 + n4 * 4);
            f32x4 iv = {im.x, im.y, im.z, im.w};
            acc[0] += fy.x * iv;
            acc[1] += fy.y * iv;
            acc[2] += fy.z * iv;
            acc[3] += fy.w * iv;
        }
        // combine the 4 y-chunks: shfl over lane^16, lane^32
#pragma unroll
        for (int j = 0; j < 4; j++) {
#pragma unroll
            for (int o = 16; o <= 32; o <<= 1) {
                acc[j].x += __shfl_xor(acc[j].x, o);
                acc[j].y += __shfl_xor(acc[j].y, o);
                acc[j].z += __shfl_xor(acc[j].z, o);
                acc[j].w += __shfl_xor(acc[j].w, o);
            }
        }
        if (ysub == 0) {
#pragma unroll
            for (int j = 0; j < 4; j++)
                *(f32x4*)(stmp + (n4 * 4 + j) * 68 + a4 * 4) = acc[j];
        }
    }
    __syncthreads();

    // stage 2: r[n][xo] = gamma * sum_a tmp[n][a] * Fx[xo][a]
    {
        const int n = tid >> 4, xo = tid & 15;
        const float* tp = stmp + n * 68;
        const float* fx = sFx + xo * 68;
        float s = 0.f;
        for (int a = 0; a < 64; a += 4) {
            float4 t4 = *(const float4*)(tp + a);
            float4 x4 = *(const float4*)(fx + a);
            s += t4.x * x4.x + t4.y * x4.y + t4.z * x4.z + t4.w * x4.w;
        }
        float v = s * gamma;
        f16 hi = (f16)v;
        size_t idx = (size_t)b * 768 + c * 256 + tid;
        r_hi[idx] = hi;
        r_lo[idx] = (f16)((v - (float)hi) * SPLIT_SC);
    }
}

// ---------------------------------------------------------------------------
// W pre-swizzle: W_ih||W_hh fp32 -> split-f16 pair in MFMA B-fragment order.
// (unchanged — verified)
// ---------------------------------------------------------------------------
__global__ __launch_bounds__(256) void swz_w(
    const float* __restrict__ W1, const float* __restrict__ W2,
    f16* __restrict__ out)
{
    const int kc = blockIdx.x >> 5, bn = blockIdx.x & 31;
    for (int t = threadIdx.x; t < 512; t += 256) {
        int c = t >> 6, lane = t & 63, l15 = lane & 15, lq = lane >> 4;
        int wrow = (c & 3) * 1024 + bn * 32 + l15 + ((c >> 2) << 4);
        const float* src;
        if (kc < 24) src = W1 + (size_t)wrow * 768 + kc * 32 + lq * 8;
        else         src = W2 + (size_t)wrow * 1024 + (kc - 24) * 32 + lq * 8;
        float4 g0 = *(const float4*)src;
        float4 g1 = *(const float4*)(src + 4);
        float gv[8] = {g0.x, g0.y, g0.z, g0.w, g1.x, g1.y, g1.z, g1.w};
        half8 hv, lv;
#pragma unroll
        for (int j = 0; j < 8; j++) {
            f16 h = (f16)gv[j];
            hv[j] = h;
            lv[j] = (f16)((gv[j] - (float)h) * SPLIT_SC);
        }
        size_t base = ((size_t)(kc * 32 + bn) * 16 + c * 2) * 512 + (size_t)lane * 8;
        *(half8*)(out + base) = hv;
        *(half8*)(out + base + 512) = lv;
    }
}

// ---------------------------------------------------------------------------
// Fused gates GEMM + LSTM pointwise, v4 (round-8 verified, 58us).
// A via LDS double-buffer, B direct from swizzled planes, 2 blocks/CU.
// ---------------------------------------------------------------------------
#define LDH 40   // LDS row stride in f16 elems (80 B)

__global__ __launch_bounds__(256, 2) void gates_lstm(
    const f16* __restrict__ A1h, const f16* __restrict__ A1l,  // r [1024][768]
    const f16* __restrict__ A2h, const f16* __restrict__ A2l,  // h [1024][1024]
    const f16* __restrict__ Wswz,                               // swizzled W
    const float* __restrict__ b1, const float* __restrict__ b2,
    float* __restrict__ cst,
    f16* __restrict__ Hh, f16* __restrict__ Hl)
{
    __shared__ f16 sA[2][2][64 * LDH];   // [buf][plane] 20.5 KB total
    const int tid = threadIdx.x;
    const int kb = blockIdx.x;           // 0..511
    const int xcd = kb & 7, jb = kb >> 3;
    const int bn = xcd * 4 + (jb & 3);   // 0..31
    const int bm = jb >> 2;              // 0..15
    const int wave = tid >> 6, lane = tid & 63;
    const int wm = (wave >> 1) * 32;
    const int cbase = (wave & 1) * 4;    // B c-tile base for this wave
    const int l15 = lane & 15, lq = lane >> 4;
    const int arow = tid >> 2, acol = (tid & 3) * 8;

    f32x4 ah[2][4], al[2][4];
#pragma unroll
    for (int i = 0; i < 2; i++)
#pragma unroll
        for (int j = 0; j < 4; j++) { ah[i][j] = (f32x4)(0.f); al[i][j] = (f32x4)(0.f); }

    // prologue: stage A(kc=0) into buf0, load B(kc=0) fragments
    {
        size_t aoff = (size_t)(bm * 64 + arow) * 768 + acol;
        *(uint4*)&sA[0][0][arow * LDH + acol] = *(const uint4*)(A1h + aoff);
        *(uint4*)&sA[0][1][arow * LDH + acol] = *(const uint4*)(A1l + aoff);
    }
    half8 Bc[8];
    {
        const f16* wb = Wswz + (size_t)bn * 16 * 512 + (size_t)lane * 8;
#pragma unroll
        for (int nt = 0; nt < 4; nt++) {
            Bc[nt * 2]     = *(const half8*)(wb + (cbase + nt) * 1024);
            Bc[nt * 2 + 1] = *(const half8*)(wb + (cbase + nt) * 1024 + 512);
        }
    }

#pragma unroll 2
    for (int i = 0; i < 56; ++i) {
        const int cur = i & 1;
        __syncthreads();                 // buf[cur] ready, prev reads drained
        const int kn = (i + 1 < 56) ? i + 1 : 55;
        // ---- prefetch A(kn) to regs ----
        const f16 *pah, *pal; int astr, ako;
        if (kn < 24) { pah = A1h; pal = A1l; astr = 768;  ako = kn * 32; }
        else         { pah = A2h; pal = A2l; astr = 1024; ako = (kn - 24) * 32; }
        size_t aoff = (size_t)(bm * 64 + arow) * astr + ako + acol;
        uint4 vh = *(const uint4*)(pah + aoff);
        uint4 vl = *(const uint4*)(pal + aoff);
        // ---- prefetch B(kn) fragments ----
        half8 Bn[8];
        {
            const f16* wb = Wswz + (size_t)(kn * 32 + bn) * 16 * 512 + (size_t)lane * 8;
#pragma unroll
            for (int nt = 0; nt < 4; nt++) {
                Bn[nt * 2]     = *(const half8*)(wb + (cbase + nt) * 1024);
                Bn[nt * 2 + 1] = *(const half8*)(wb + (cbase + nt) * 1024 + 512);
            }
        }
        // ---- compute on buf[cur] with Bc ----
        half8 afh[2], afl[2];
#pragma unroll
        for (int mt = 0; mt < 2; mt++) {
            int ro = (wm + mt * 16 + l15) * LDH + lq * 8;
            afh[mt] = *(const half8*)&sA[cur][0][ro];
            afl[mt] = *(const half8*)&sA[cur][1][ro];
        }
#pragma unroll
        for (int mt = 0; mt < 2; mt++)
#pragma unroll
            for (int nt = 0; nt < 4; nt++) {
                ah[mt][nt] = __builtin_amdgcn_mfma_f32_16x16x32_f16(
                    afh[mt], Bc[nt * 2], ah[mt][nt], 0, 0, 0);
                al[mt][nt] = __builtin_amdgcn_mfma_f32_16x16x32_f16(
                    afh[mt], Bc[nt * 2 + 1], al[mt][nt], 0, 0, 0);
                al[mt][nt] = __builtin_amdgcn_mfma_f32_16x16x32_f16(
                    afl[mt], Bc[nt * 2], al[mt][nt], 0, 0, 0);
            }
        // ---- write prefetched A into the other buffer, rotate B ----
        const int nxt = cur ^ 1;
        *(uint4*)&sA[nxt][0][arow * LDH + acol] = vh;
        *(uint4*)&sA[nxt][1][arow * LDH + acol] = vl;
#pragma unroll
        for (int q = 0; q < 8; q++) Bc[q] = Bn[q];
    }

    // epilogue: lane owns gates {i,f,g,o} = nt at unit u (verified)
    const int u = bn * 32 + l15 + ((wave & 1) << 4);
    float bvs[4];
#pragma unroll
    for (int g = 0; g < 4; g++) bvs[g] = b1[g * 1024 + u] + b2[g * 1024 + u];
#pragma unroll
    for (int mt = 0; mt < 2; mt++) {
#pragma unroll
        for (int rg = 0; rg < 4; rg++) {
            int row = bm * 64 + wm + mt * 16 + lq * 4 + rg;
            size_t idx = (size_t)row * 1024 + u;
            float gi = ah[mt][0][rg] + al[mt][0][rg] * SPLIT_INV + bvs[0];
            float gf = ah[mt][1][rg] + al[mt][1][rg] * SPLIT_INV + bvs[1];
            float gg = ah[mt][2][rg] + al[mt][2][rg] * SPLIT_INV + bvs[2];
            float go = ah[mt][3][rg] + al[mt][3][rg] * SPLIT_INV + bvs[3];
            float cn = sigf(gf) * cst[idx] + sigf(gi) * tanhf(gg);
            float hn = sigf(go) * tanhf(cn);
            cst[idx] = cn;
            f16 hh = (f16)hn;
            Hh[idx] = hh;
            Hl[idx] = (f16)((hn - (float)hh) * SPLIT_SC);
        }
    }
}

// ---------------------------------------------------------------------------
// fc0 v3: t = relu(h @ W_fc0^T + b), split-f16 3-pass, 64x64 tiles,
// grid (16,16) = 256 blocks (was 64 -> 75% CUs idle).
// ---------------------------------------------------------------------------
__global__ __launch_bounds__(256) void fc0_gemm(
    const f16* __restrict__ Ah, const f16* __restrict__ Al,
    const float* __restrict__ W, const float* __restrict__ bias,
    float* __restrict__ out)
{
    __shared__ f16 sAh[64 * LDH], sAl[64 * LDH];
    __shared__ f16 sBh[64 * LDH], sBl[64 * LDH];
    const int tid = threadIdx.x;
    const int bm = blockIdx.x, bn = blockIdx.y;
    const int wave = tid >> 6, lane = tid & 63;
    const int wm = (wave >> 1) * 32, wn = (wave & 1) * 32;
    const int l15 = lane & 15, lq = lane >> 4;

    f32x4 ach[2][2], acx[2][2];
#pragma unroll
    for (int i = 0; i < 2; i++)
#pragma unroll
        for (int j = 0; j < 2; j++) { ach[i][j] = (f32x4)(0.f); acx[i][j] = (f32x4)(0.f); }

    for (int kc = 0; kc < 1024; kc += 32) {
        {
            int e = tid * 8;
            int row = e >> 5, col = e & 31;
            size_t off = (size_t)(bm * 64 + row) * 1024 + kc + col;
            *(uint4*)&sAh[row * LDH + col] = *(const uint4*)(Ah + off);
            *(uint4*)&sAl[row * LDH + col] = *(const uint4*)(Al + off);
        }
#pragma unroll
        for (int l = 0; l < 2; l++) {
            int e = (l * 256 + tid) * 4;
            int crow = e >> 5, col = e & 31;
            float4 g = *(const float4*)(W + (size_t)(bn * 64 + crow) * 1024 + kc + col);
            f16 h0 = (f16)g.x, h1 = (f16)g.y, h2 = (f16)g.z, h3 = (f16)g.w;
            half4 hv = {h0, h1, h2, h3};
            half4 lv = {(f16)((g.x - (float)h0) * SPLIT_SC),
                        (f16)((g.y - (float)h1) * SPLIT_SC),
                        (f16)((g.z - (float)h2) * SPLIT_SC),
                        (f16)((g.w - (float)h3) * SPLIT_SC)};
            *(half4*)&sBh[crow * LDH + col] = hv;
            *(half4*)&sBl[crow * LDH + col] = lv;
        }
        __syncthreads();
        half8 afh[2], afl[2], bfh[2], bfl[2];
#pragma unroll
        for (int mt = 0; mt < 2; mt++) {
            int ro = (wm + mt * 16 + l15) * LDH + lq * 8;
            afh[mt] = *(const half8*)&sAh[ro];
            afl[mt] = *(const half8*)&sAl[ro];
        }
#pragma unroll
        for (int nt = 0; nt < 2; nt++) {
            int ro = (wn + nt * 16 + l15) * LDH + lq * 8;
            bfh[nt] = *(const half8*)&sBh[ro];
            bfl[nt] = *(const half8*)&sBl[ro];
        }
#pragma unroll
        for (int mt = 0; mt < 2; mt++)
#pragma unroll
            for (int nt = 0; nt < 2; nt++) {
                ach[mt][nt] = __builtin_amdgcn_mfma_f32_16x16x32_f16(
                    afh[mt], bfh[nt], ach[mt][nt], 0, 0, 0);
                acx[mt][nt] = __builtin_amdgcn_mfma_f32_16x16x32_f16(
                    afh[mt], bfl[nt], acx[mt][nt], 0, 0, 0);
                acx[mt][nt] = __builtin_amdgcn_mfma_f32_16x16x32_f16(
                    afl[mt], bfh[nt], acx[mt][nt], 0, 0, 0);
            }
        __syncthreads();
    }

#pragma unroll
    for (int mt = 0; mt < 2; mt++) {
#pragma unroll
        for (int nt = 0; nt < 2; nt++) {
            int col = bn * 64 + wn + nt * 16 + l15;
            float bv = bias[col];
#pragma unroll
            for (int rg = 0; rg < 4; rg++) {
                int row = bm * 64 + wm + mt * 16 + lq * 4 + rg;
                float v = ach[mt][nt][rg] + acx[mt][nt][rg] * SPLIT_INV + bv;
                out[(size_t)row * 1024 + col] = fmaxf(v, 0.f);
            }
        }
    }
}

// ---------------------------------------------------------------------------
// final tiny fc: out[b][j] = t[b] . W_fc[j] + b_fc[j], j < 10, fp32 out
// ---------------------------------------------------------------------------
__global__ __launch_bounds__(64) void fc_out(
    const float* __restrict__ tb, const float* __restrict__ Wfc,
    const float* __restrict__ bfc, float* __restrict__ out)
{
    int b = blockIdx.x, lane = threadIdx.x;
    const float* tv = tb + (size_t)b * 1024;
    float p[10];
#pragma unroll
    for (int j = 0; j < 10; j++) p[j] = 0.f;
    for (int k = lane; k < 1024; k += 64) {
        float t = tv[k];
#pragma unroll
        for (int j = 0; j < 10; j++) p[j] += t * Wfc[j * 1024 + k];
    }
#pragma unroll
    for (int j = 0; j < 10; j++) {
#pragma unroll
        for (int o = 32; o > 0; o >>= 1) p[j] += __shfl_xor(p[j], o);
    }
    if (lane == 0) {
#pragma unroll
        for (int j = 0; j < 10; j++) out[b * 10 + j] = p[j] + bfc[j];
    }
}

extern "C" void kernel_launch(void* const* d_in, const int* in_sizes, int n_in,
                              void* d_out, int out_size, void* d_ws, size_t ws_size,
                              hipStream_t stream)
{
    const float* x     = (const float*)d_in[0];
    const float* W_att = (const float*)d_in[1];
    const float* b_att = (const float*)d_in[2];
    const float* W_ih  = (const float*)d_in[3];
    const float* W_hh  = (const float*)d_in[4];
    const float* b_ih  = (const float*)d_in[5];
    const float* b_hh  = (const float*)d_in[6];
    const float* W_fc0 = (const float*)d_in[7];
    const float* b_fc0 = (const float*)d_in[8];
    const float* W_fc  = (const float*)d_in[9];
    const float* b_fc  = (const float*)d_in[10];
    float* out = (float*)d_out;

    // Workspace (~44.5 MB, round-8 verified): Wswz | c | h planes x4 | r x2
    char* ws = (char*)d_ws;
    f16*   Wswz   = (f16*)ws;    ws += (size_t)56 * 32 * 16 * 512 * 2;  // 29.36 MB
    float* c_f32  = (float*)ws;  ws += (size_t)1024 * 1024 * 4;         // 4 MB
    f16*   h_hi0  = (f16*)ws;    ws += (size_t)1024 * 1024 * 2;
    f16*   h_hi1  = (f16*)ws;    ws += (size_t)1024 * 1024 * 2;
    f16*   h_lo0  = (f16*)ws;    ws += (size_t)1024 * 1024 * 2;
    f16*   h_lo1  = (f16*)ws;    ws += (size_t)1024 * 1024 * 2;
    f16*   r_hi   = (f16*)ws;    ws += (size_t)1024 * 768 * 2;
    f16*   r_lo   = (f16*)ws;    ws += (size_t)1024 * 768 * 2;
    float* t_f32  = c_f32;  // overlay: c dead after last gates_lstm
    f16* h_hi[2] = {h_hi0, h_hi1};
    f16* h_lo[2] = {h_lo0, h_lo1};

    hipMemsetAsync(c_f32, 0, (size_t)1024 * 1024 * 4, stream);
    hipMemsetAsync(h_hi0, 0, (size_t)1024 * 1024 * 2, stream);
    hipMemsetAsync(h_lo0, 0, (size_t)1024 * 1024 * 2, stream);

    swz_w<<<56 * 32, 256, 0, stream>>>(W_ih, W_hh, Wswz);

    for (int t = 0; t < 16; t++) {
        int rb = t & 1, wb = 1 - rb;
        att_glimpse<<<dim3(1024, 3), 256, 0, stream>>>(
            h_hi[rb], h_lo[rb], W_att, b_att, x, r_hi, r_lo);
        gates_lstm<<<512, 256, 0, stream>>>(
            r_hi, r_lo, h_hi[rb], h_lo[rb], Wswz, b_ih, b_hh,
            c_f32, h_hi[wb], h_lo[wb]);
    }
    fc0_gemm<<<dim3(16, 16), 256, 0, stream>>>(
        h_hi[0], h_lo[0], W_fc0, b_fc0, t_f32);
    fc_out<<<1024, 64, 0, stream>>>(t_f32, W_fc, b_fc, out);
}